// Round 1
// baseline (692.174 us; speedup 1.0000x reference)
//
#include <hip/hip_runtime.h>
#include <hip/hip_bf16.h>

#define FEATURE_DIM 512
#define CLASS_NUM   100000
#define BATCH       512
#define CPAD        100096   // 782 * 128
#define SCALE       30.0f
#define MARGIN      0.5f

typedef unsigned short u16;
typedef __attribute__((ext_vector_type(8))) short bf16x8;
typedef __attribute__((ext_vector_type(4))) float f32x4;

__device__ __forceinline__ u16 f32_to_bf16(float f) {
    unsigned int x = __builtin_bit_cast(unsigned int, f);
    unsigned int r = (x + 0x7fffu + ((x >> 16) & 1u)) >> 16;
    return (u16)r;
}

#define GLL(g, l) __builtin_amdgcn_global_load_lds( \
    (const __attribute__((address_space(1))) void*)(g), \
    (__attribute__((address_space(3))) void*)(l), 16, 0, 0)

// ---------------------------------------------------------------------------
// Normalize rows of src [R][512] fp32 -> dst [Rpad][512] bf16, one wave/row.
// Rows >= R (padding) are zeroed. Per-block sum of norms -> partials[block].
// ---------------------------------------------------------------------------
__global__ __launch_bounds__(256) void normalize_rows(
    const float* __restrict__ src, u16* __restrict__ dst,
    float* __restrict__ partials, int R)
{
    const int tid  = threadIdx.x;
    const int wid  = tid >> 6;
    const int lane = tid & 63;
    const int row  = blockIdx.x * 4 + wid;
    __shared__ float s_norm[4];

    float norm = 0.0f;
    u16* drow = dst + (size_t)row * FEATURE_DIM;
    if (row < R) {
        const float4* p = (const float4*)(src + (size_t)row * FEATURE_DIM);
        float4 a = p[lane];
        float4 b = p[lane + 64];
        float ss = a.x*a.x + a.y*a.y + a.z*a.z + a.w*a.w
                 + b.x*b.x + b.y*b.y + b.z*b.z + b.w*b.w;
        #pragma unroll
        for (int o = 32; o > 0; o >>= 1) ss += __shfl_xor(ss, o, 64);
        norm = sqrtf(ss);
        float inv = 1.0f / norm;
        ushort4 pa, pb;
        pa.x = f32_to_bf16(a.x * inv); pa.y = f32_to_bf16(a.y * inv);
        pa.z = f32_to_bf16(a.z * inv); pa.w = f32_to_bf16(a.w * inv);
        pb.x = f32_to_bf16(b.x * inv); pb.y = f32_to_bf16(b.y * inv);
        pb.z = f32_to_bf16(b.z * inv); pb.w = f32_to_bf16(b.w * inv);
        ushort4* q = (ushort4*)drow;
        q[lane]      = pa;
        q[lane + 64] = pb;
    } else {
        ushort4 z = {0, 0, 0, 0};
        ushort4* q = (ushort4*)drow;
        q[lane]      = z;
        q[lane + 64] = z;
    }
    if (lane == 0) s_norm[wid] = norm;
    __syncthreads();
    if (tid == 0)
        partials[blockIdx.x] = s_norm[0] + s_norm[1] + s_norm[2] + s_norm[3];
}

// ---------------------------------------------------------------------------
// GEMM: cos[m][n] = sum_k nfeat[m][k] * nw[n][k]   (both row-major in K)
// Block tile 256(M) x 128(N), BK=32, 512 threads = 8 waves (4x2), each wave
// 64x64 via 4x4 mfma_f32_16x16x32_bf16. m97-style global_load_lds staging.
// Fused epilogue: cos and 30*cos (margin fixed up later at label cols only).
// ---------------------------------------------------------------------------
__global__ __launch_bounds__(512, 2) void gemm_kernel(
    const u16* __restrict__ A,   // nfeat [512][512]
    const u16* __restrict__ B,   // nw    [CPAD][512]
    float* __restrict__ cosO, float* __restrict__ logO)
{
    __shared__ u16 As[256 * 32];
    __shared__ u16 Bs[128 * 32];

    const int tid  = threadIdx.x;
    const int n0   = blockIdx.x * 128;
    const int m0   = blockIdx.y * 256;
    const int wid  = tid >> 6;
    const int lane = tid & 63;
    const int wm   = (wid & 3) << 6;   // wave m offset: 0,64,128,192
    const int wn   = (wid >> 2) << 6;  // wave n offset: 0,64
    const int quad = lane >> 4;
    const int l15  = lane & 15;

    f32x4 acc[4][4];
    #pragma unroll
    for (int i = 0; i < 4; ++i)
        #pragma unroll
        for (int j = 0; j < 4; ++j)
            acc[i][j] = (f32x4){0.f, 0.f, 0.f, 0.f};

    const int srow = tid >> 2;         // 0..127
    const int scol = (tid & 3) * 8;    // 0,8,16,24
    const u16* gA0 = A + (size_t)(m0 + srow) * FEATURE_DIM + scol;
    const u16* gA1 = gA0 + 128 * FEATURE_DIM;
    const u16* gB  = B + (size_t)(n0 + srow) * FEATURE_DIM + scol;
    u16* lA0 = As + (size_t)tid * 8;
    u16* lA1 = As + (size_t)(512 + tid) * 8;
    u16* lB  = Bs + (size_t)tid * 8;

    for (int k0 = 0; k0 < FEATURE_DIM; k0 += 32) {
        GLL(gA0 + k0, lA0);
        GLL(gA1 + k0, lA1);
        GLL(gB  + k0, lB);
        __syncthreads();   // drains vmcnt -> LDS tiles valid

        bf16x8 af[4], bfr[4];
        #pragma unroll
        for (int mi = 0; mi < 4; ++mi)
            af[mi] = *(const bf16x8*)(As + (wm + mi * 16 + l15) * 32 + quad * 8);
        #pragma unroll
        for (int ni = 0; ni < 4; ++ni)
            bfr[ni] = *(const bf16x8*)(Bs + (wn + ni * 16 + l15) * 32 + quad * 8);

        #pragma unroll
        for (int mi = 0; mi < 4; ++mi)
            #pragma unroll
            for (int ni = 0; ni < 4; ++ni)
                acc[mi][ni] = __builtin_amdgcn_mfma_f32_16x16x32_bf16(
                    af[mi], bfr[ni], acc[mi][ni], 0, 0, 0);
        __syncthreads();   // LDS reads done before next stage overwrites
    }

    // Epilogue. C/D layout: col = lane&15, row = quad*4 + reg.
    #pragma unroll
    for (int ni = 0; ni < 4; ++ni) {
        int gc = n0 + wn + ni * 16 + l15;
        if (gc < CLASS_NUM) {
            #pragma unroll
            for (int mi = 0; mi < 4; ++mi) {
                int gr0 = m0 + wm + mi * 16 + quad * 4;
                f32x4 v = acc[mi][ni];
                #pragma unroll
                for (int r = 0; r < 4; ++r) {
                    size_t idx = (size_t)(gr0 + r) * CLASS_NUM + gc;
                    cosO[idx] = v[r];
                    logO[idx] = SCALE * v[r];
                }
            }
        }
    }
}

// ---------------------------------------------------------------------------
// Stats + margin fixup. One block, 512 threads (one per batch row).
// ---------------------------------------------------------------------------
__global__ __launch_bounds__(512) void stats_kernel(
    const float* __restrict__ cosO, float* __restrict__ logO,
    const int* __restrict__ label,
    const float* __restrict__ pw, int npw,
    const float* __restrict__ px, int npx,
    float* __restrict__ scal)
{
    const int tid  = threadIdx.x;
    const int wid  = tid >> 6;
    const int lane = tid & 63;

    __shared__ float r_sum[8], r_min[8], r_max[8], r_w[8], r_x[8], r_var[8];
    __shared__ float s_avg;

    int lab = label[tid];
    lab = max(0, min(CLASS_NUM - 1, lab));
    float x = cosO[(size_t)tid * CLASS_NUM + lab];

    const float cosm = 0.8775825618903728f;   // cos(0.5)
    const float sinm = 0.4794255386042030f;   // sin(0.5)
    float lg;
    if (x > -cosm)
        lg = SCALE * (x * cosm - sinm * sqrtf(fmaxf(0.f, 1.f - x * x)));
    else
        lg = SCALE * (x - MARGIN * sinm);
    logO[(size_t)tid * CLASS_NUM + lab] = lg;

    float xc = fminf(1.f, fmaxf(-1.f, x));
    float theta = acosf(xc) * 57.29577951308232f;   // deg

    float sw = 0.f;
    for (int i = tid; i < npw; i += 512) sw += pw[i];
    float sx = (tid < npx) ? px[tid] : 0.f;

    float s = theta, mn = theta, mx = theta;
    #pragma unroll
    for (int o = 32; o > 0; o >>= 1) {
        s  += __shfl_xor(s, o, 64);
        mn  = fminf(mn, __shfl_xor(mn, o, 64));
        mx  = fmaxf(mx, __shfl_xor(mx, o, 64));
        sw += __shfl_xor(sw, o, 64);
        sx += __shfl_xor(sx, o, 64);
    }
    if (lane == 0) {
        r_sum[wid] = s; r_min[wid] = mn; r_max[wid] = mx;
        r_w[wid] = sw; r_x[wid] = sx;
    }
    __syncthreads();
    if (tid == 0) {
        float ts = 0.f, tmn = r_min[0], tmx = r_max[0], tw = 0.f, tx = 0.f;
        #pragma unroll
        for (int i = 0; i < 8; ++i) {
            ts += r_sum[i];
            tmn = fminf(tmn, r_min[i]);
            tmx = fmaxf(tmx, r_max[i]);
            tw += r_w[i];
            tx += r_x[i];
        }
        float avg = ts * (1.0f / BATCH);
        s_avg = avg;
        scal[0] = avg;                       // avg_theta
        scal[1] = tmn;                       // min_theta
        scal[2] = tmx;                       // max_theta
        scal[4] = tw * (1.0f / CLASS_NUM);   // avg_w_norm
        scal[5] = tx * (1.0f / BATCH);       // avg_x_norm
    }
    __syncthreads();
    float d = theta - s_avg;
    float v = d * d;
    #pragma unroll
    for (int o = 32; o > 0; o >>= 1) v += __shfl_xor(v, o, 64);
    if (lane == 0) r_var[wid] = v;
    __syncthreads();
    if (tid == 0) {
        float tv = 0.f;
        #pragma unroll
        for (int i = 0; i < 8; ++i) tv += r_var[i];
        scal[3] = sqrtf(tv / (BATCH - 1));   // stdv_theta
    }
}

// ---------------------------------------------------------------------------
extern "C" void kernel_launch(void* const* d_in, const int* in_sizes, int n_in,
                              void* d_out, int out_size, void* d_ws, size_t ws_size,
                              hipStream_t stream)
{
    const float* feat    = (const float*)d_in[0];
    const float* weights = (const float*)d_in[1];
    const int*   label   = (const int*)d_in[2];

    float* out  = (float*)d_out;
    float* cosO = out;
    float* logO = out + (size_t)BATCH * CLASS_NUM;
    float* scal = out + 2 * (size_t)BATCH * CLASS_NUM;

    // workspace layout
    const size_t nfeat_bytes = (size_t)BATCH * FEATURE_DIM * sizeof(u16);   // 512 KiB
    const size_t nw_bytes    = (size_t)CPAD * FEATURE_DIM * sizeof(u16);    // ~102.5 MB
    const size_t need = nfeat_bytes + nw_bytes + (128 + CPAD / 4) * sizeof(float);
    if (ws_size < need) return;  // loud failure rather than OOB corruption

    char* ws    = (char*)d_ws;
    u16*  nfeat = (u16*)ws;
    u16*  nw    = (u16*)(ws + nfeat_bytes);
    float* px   = (float*)(ws + nfeat_bytes + nw_bytes);
    float* pw   = px + 128;

    normalize_rows<<<BATCH / 4, 256, 0, stream>>>(feat, nfeat, px, BATCH);
    normalize_rows<<<CPAD / 4, 256, 0, stream>>>(weights, nw, pw, CLASS_NUM);

    dim3 grid(CPAD / 128, BATCH / 256);
    gemm_kernel<<<grid, 512, 0, stream>>>(nfeat, nw, cosO, logO);

    stats_kernel<<<1, 512, 0, stream>>>(cosO, logO, label,
                                        pw, CPAD / 4, px, BATCH / 4, scal);
}